// Round 3
// baseline (290.699 us; speedup 1.0000x reference)
//
#include <hip/hip_runtime.h>
#include <math.h>

// Problem: B=16384, D=512, R=64, E=8.
// out = x0 * (sum_e g_e * (x @ V[e]^T C[e] U[e]^T)) + g@b + x*sum(g)
// Folded: VC[d, e*R+s] = sum_r V[e,r,d] C[e,r,s]  ->  xvc = x @ VC   (GEMM1)
//         t = g-scaled xvc (expert = col/64)      ->  gproj = t @ Ustack (GEMM2)
// R3: ping-pong global->VGPR->ds_write pipeline (no global_load_lds, no vmcnt(0)
//     drain at barriers); epilogue g/b staged via LDS (kills 128 scalar VMEM
//     loads/thread). 128x64 tiles, grid (128,8), 4 blocks/CU target.

typedef __bf16 bf16_t;
typedef __attribute__((ext_vector_type(8))) __bf16 bf16x8;
typedef __attribute__((ext_vector_type(4))) __bf16 bf16x4;
typedef __attribute__((ext_vector_type(4))) float  floatx4;

// ---------------- K0: weight prep ------------------------------------------
__global__ __launch_bounds__(256) void prep_kernel(
    const float* __restrict__ U, const float* __restrict__ V, const float* __restrict__ C,
    bf16_t* __restrict__ VCc, bf16_t* __restrict__ Ut) {
  int tid = blockIdx.x * 256 + threadIdx.x;
  if (tid < 512 * 512) {
    int n = tid >> 9, d = tid & 511;
    int e = n >> 6, s = n & 63;
    const float* Vp = V + (size_t)e * 64 * 512 + d;   // V[e,r,d], stride 512 over r
    const float* Cp = C + (size_t)e * 64 * 64 + s;    // C[e,r,s], stride 64 over r
    float acc = 0.f;
#pragma unroll 8
    for (int r = 0; r < 64; ++r) acc += Vp[(size_t)r * 512] * Cp[r * 64];
    VCc[tid] = (bf16_t)acc;
  } else {
    int i2 = tid - 512 * 512;
    int d = i2 >> 9, n = i2 & 511;
    int e = n >> 6, s = n & 63;
    Ut[i2] = (bf16_t)U[((size_t)e * 512 + d) * 64 + s];
  }
}

// ---------------- K1: x -> bf16 cast + gate softmax (one wave per row) -----
__global__ __launch_bounds__(256) void gate_kernel(
    const float* __restrict__ x, const float* __restrict__ Wg, const float* __restrict__ bg,
    bf16_t* __restrict__ xbf, float* __restrict__ g) {
  int wave = threadIdx.x >> 6, lane = threadIdx.x & 63;
  int row = blockIdx.x * 4 + wave;
  const float4* xr = (const float4*)(x + (size_t)row * 512);
  float4 v0 = xr[lane];
  float4 v1 = xr[lane + 64];
  bf16x4* xb = (bf16x4*)(xbf + (size_t)row * 512);
  bf16x4 b0, b1;
  b0.x = (bf16_t)v0.x; b0.y = (bf16_t)v0.y; b0.z = (bf16_t)v0.z; b0.w = (bf16_t)v0.w;
  b1.x = (bf16_t)v1.x; b1.y = (bf16_t)v1.y; b1.z = (bf16_t)v1.z; b1.w = (bf16_t)v1.w;
  xb[lane] = b0;
  xb[lane + 64] = b1;
  float acc[8];
#pragma unroll
  for (int e = 0; e < 8; ++e) {
    const float4* wp = (const float4*)(Wg + (size_t)e * 512);
    float4 w0 = wp[lane], w1 = wp[lane + 64];
    acc[e] = v0.x * w0.x + v0.y * w0.y + v0.z * w0.z + v0.w * w0.w +
             v1.x * w1.x + v1.y * w1.y + v1.z * w1.z + v1.w * w1.w;
  }
#pragma unroll
  for (int e = 0; e < 8; ++e) {
#pragma unroll
    for (int off = 32; off > 0; off >>= 1) acc[e] += __shfl_xor(acc[e], off, 64);
  }
  float z[8], mx = -1e30f;
#pragma unroll
  for (int e = 0; e < 8; ++e) { z[e] = acc[e] + bg[e]; mx = fmaxf(mx, z[e]); }
  float s = 0.f;
#pragma unroll
  for (int e = 0; e < 8; ++e) { z[e] = __expf(z[e] - mx); s += z[e]; }
  float inv = 1.f / s;
  if (lane == 0) {
#pragma unroll
    for (int e = 0; e < 8; ++e) g[(size_t)row * 8 + e] = z[e] * inv;
  }
}

// ---------------- pipelined GEMM core: 128x64 tile, BK=64, 4 waves ---------
// A [M][512] bf16 row-major; Bt [N][512] bf16 (column n's K contiguous).
// LDS layout: row r's 8 16B-chunks stored permuted: slot q holds chunk q^(r&7).
// ds_write: thread t writes chunk q=t&7 of row r=t>>3 (+32/chunk-idx) -> each
// wave covers contiguous 1KB (8 rows x 128B permuted in-row) = min bank touch.
// Fragment ds_read_b128: addr = r*128 + ((kq^(llo&7))<<4) -> 16 lanes hit 8
// distinct chunk columns twice = 2-way = free (m136).
struct StageRegs { float4 a[4]; float4 b[2]; };

__device__ __forceinline__ void load_tile(const char* gA, const char* gB, int it, StageRegs& s) {
#pragma unroll
  for (int i = 0; i < 4; ++i)
    s.a[i] = *(const float4*)(gA + it * 128 + (size_t)i * 32 * 1024);
#pragma unroll
  for (int j = 0; j < 2; ++j)
    s.b[j] = *(const float4*)(gB + it * 128 + (size_t)j * 32 * 1024);
}

__device__ __forceinline__ void write_tile(char* wA, char* wB, const StageRegs& s) {
#pragma unroll
  for (int i = 0; i < 4; ++i) *(float4*)(wA + i * 32 * 128) = s.a[i];
#pragma unroll
  for (int j = 0; j < 2; ++j) *(float4*)(wB + j * 32 * 128) = s.b[j];
}

__device__ __forceinline__ void compute_tile(const char* ldsA, const char* ldsB,
                                             int wr, int wc, int lhi, int llo,
                                             floatx4 acc[4][2]) {
#pragma unroll
  for (int ks = 0; ks < 2; ++ks) {
    const int sw = (((ks * 4 + lhi) ^ (llo & 7)) << 4);
    bf16x8 bfm[2];
#pragma unroll
    for (int j = 0; j < 2; ++j)
      bfm[j] = *(const bf16x8*)(ldsB + (wc * 32 + j * 16 + llo) * 128 + sw);
#pragma unroll
    for (int i = 0; i < 4; ++i) {
      bf16x8 af = *(const bf16x8*)(ldsA + (wr * 64 + i * 16 + llo) * 128 + sw);
      acc[i][0] = __builtin_amdgcn_mfma_f32_16x16x32_bf16(af, bfm[0], acc[i][0], 0, 0, 0);
      acc[i][1] = __builtin_amdgcn_mfma_f32_16x16x32_bf16(af, bfm[1], acc[i][1], 0, 0, 0);
    }
  }
}

__device__ __forceinline__ void gemm_pipe(const bf16_t* A, const bf16_t* Bt,
                                          int m0, int n0, int t,
                                          char* ldsA, char* ldsB, floatx4 acc[4][2]) {
  const int lane = t & 63;
  const int wr = t >> 7, wc = (t >> 6) & 1;
  const int lhi = lane >> 4, llo = lane & 15;
  const int rs = t >> 3, qs = t & 7;
  const char* gA = (const char*)A + (size_t)(m0 + rs) * 1024 + qs * 16;
  const char* gB = (const char*)Bt + (size_t)(n0 + rs) * 1024 + qs * 16;
  char* wA = ldsA + rs * 128 + ((qs ^ (rs & 7)) << 4);
  char* wB = ldsB + rs * 128 + ((qs ^ (rs & 7)) << 4);
  StageRegs r0, r1;
  load_tile(gA, gB, 0, r0);
#pragma unroll 1
  for (int it = 0; it < 8; it += 2) {
    write_tile(wA, wB, r0);            // vmcnt wait here, hidden by prev compute
    __syncthreads();                   // writes visible
    load_tile(gA, gB, it + 1, r1);     // next tile in flight across compute
    compute_tile(ldsA, ldsB, wr, wc, lhi, llo, acc);   // tile it
    __syncthreads();                   // readers done before next write
    write_tile(wA, wB, r1);
    __syncthreads();
    load_tile(gA, gB, (it + 2 < 8) ? it + 2 : 0, r0);  // clamped (tail: harmless)
    compute_tile(ldsA, ldsB, wr, wc, lhi, llo, acc);   // tile it+1
    __syncthreads();
  }
}

// ---------------- K2: GEMM1 + gate-scale epilogue -> t (bf16) --------------
__global__ __launch_bounds__(256, 4) void gemm1_kernel(
    const bf16_t* __restrict__ xbf, const bf16_t* __restrict__ VCc,
    const float* __restrict__ g, bf16_t* __restrict__ T) {
  __shared__ char lds[24576];
  int t = threadIdx.x;
  int m0 = blockIdx.x * 128, n0 = blockIdx.y * 64;
  floatx4 acc[4][2];
#pragma unroll
  for (int i = 0; i < 4; ++i)
#pragma unroll
    for (int j = 0; j < 2; ++j) acc[i][j] = (floatx4){0.f, 0.f, 0.f, 0.f};
  gemm_pipe(xbf, VCc, m0, n0, t, lds, lds + 16384, acc);
  // stage this block's gate column (expert e = n0/64) into LDS
  float* ldsG = (float*)lds;
  const int e = n0 >> 6;
  if (t < 128) ldsG[t] = g[(size_t)(m0 + t) * 8 + e];
  __syncthreads();
  const int lane = t & 63;
  const int wr = t >> 7, wc = (t >> 6) & 1;
  const int lhi = lane >> 4, llo = lane & 15;
#pragma unroll
  for (int i = 0; i < 4; ++i) {
#pragma unroll
    for (int r = 0; r < 4; ++r) {
      int rml = wr * 64 + i * 16 + lhi * 4 + r;    // C/D: col=lane&15, row=quad*4+reg
      float gv = ldsG[rml];
      int m = m0 + rml;
#pragma unroll
      for (int j = 0; j < 2; ++j) {
        int n = n0 + wc * 32 + j * 16 + llo;
        T[(size_t)m * 512 + n] = (bf16_t)(acc[i][j][r] * gv);
      }
    }
  }
}

// ---------------- K3: GEMM2 + final epilogue -> out (f32) ------------------
__global__ __launch_bounds__(256, 4) void gemm2_kernel(
    const bf16_t* __restrict__ T, const bf16_t* __restrict__ Ut,
    const float* __restrict__ g, const float* __restrict__ bvec,
    const float* __restrict__ x0, const float* __restrict__ x,
    float* __restrict__ out) {
  __shared__ char lds[24576];
  int t = threadIdx.x;
  int m0 = blockIdx.x * 128, n0 = blockIdx.y * 64;
  floatx4 acc[4][2];
#pragma unroll
  for (int i = 0; i < 4; ++i)
#pragma unroll
    for (int j = 0; j < 2; ++j) acc[i][j] = (floatx4){0.f, 0.f, 0.f, 0.f};
  gemm_pipe(T, Ut, m0, n0, t, lds, lds + 16384, acc);
  // stage g-slab [128][8] (4KB) and b-slab [8][64] (2KB) into LDS
  float* ldsG = (float*)lds;                 // 1024 floats
  float* ldsBv = (float*)(lds + 4096);       // 512 floats, layout [e][64]
  ((float4*)ldsG)[t] = ((const float4*)(g + (size_t)m0 * 8))[t];
  if (t < 128)
    ((float4*)ldsBv)[t] = ((const float4*)bvec)[(t >> 4) * 128 + (n0 >> 2) + (t & 15)];
  __syncthreads();
  const int lane = t & 63;
  const int wr = t >> 7, wc = (t >> 6) & 1;
  const int lhi = lane >> 4, llo = lane & 15;
  float bb[2][8];
#pragma unroll
  for (int j = 0; j < 2; ++j) {
    int nl = wc * 32 + j * 16 + llo;
#pragma unroll
    for (int e = 0; e < 8; ++e) bb[j][e] = ldsBv[e * 64 + nl];
  }
#pragma unroll
  for (int i = 0; i < 4; ++i) {
#pragma unroll
    for (int r = 0; r < 4; ++r) {
      int rml = wr * 64 + i * 16 + lhi * 4 + r;
      float4 ga = ((const float4*)ldsG)[rml * 2];
      float4 gb2 = ((const float4*)ldsG)[rml * 2 + 1];
      float g8[8] = {ga.x, ga.y, ga.z, ga.w, gb2.x, gb2.y, gb2.z, gb2.w};
      float gsum = g8[0] + g8[1] + g8[2] + g8[3] + g8[4] + g8[5] + g8[6] + g8[7];
      int m = m0 + rml;
#pragma unroll
      for (int j = 0; j < 2; ++j) {
        int n = n0 + wc * 32 + j * 16 + llo;
        float bias = 0.f;
#pragma unroll
        for (int e = 0; e < 8; ++e) bias += g8[e] * bb[j][e];
        size_t idx = (size_t)m * 512 + n;
        out[idx] = x0[idx] * acc[i][j][r] + bias + x[idx] * gsum;
      }
    }
  }
}

// ---------------- launch ----------------------------------------------------
extern "C" void kernel_launch(void* const* d_in, const int* in_sizes, int n_in,
                              void* d_out, int out_size, void* d_ws, size_t ws_size,
                              hipStream_t stream) {
  const float* x0 = (const float*)d_in[0];
  const float* x  = (const float*)d_in[1];
  const float* U  = (const float*)d_in[2];
  const float* V  = (const float*)d_in[3];
  const float* C  = (const float*)d_in[4];
  const float* bv = (const float*)d_in[5];
  const float* Wg = (const float*)d_in[6];
  const float* bg = (const float*)d_in[7];
  float* out = (float*)d_out;

  char* ws = (char*)d_ws;
  bf16_t* xbf = (bf16_t*)(ws);                               // 16,777,216 B
  bf16_t* T   = (bf16_t*)(ws + 16777216);                    // 16,777,216 B
  bf16_t* VCc = (bf16_t*)(ws + 33554432);                    //    524,288 B
  bf16_t* Ut  = (bf16_t*)(ws + 34078720);                    //    524,288 B
  float*  g   = (float*)(ws + 34603008);                     //    524,288 B

  prep_kernel<<<2048, 256, 0, stream>>>(U, V, C, VCc, Ut);
  gate_kernel<<<4096, 256, 0, stream>>>(x, Wg, bg, xbf, g);
  gemm1_kernel<<<dim3(128, 8), 256, 0, stream>>>(xbf, VCc, g, T);
  gemm2_kernel<<<dim3(128, 8), 256, 0, stream>>>(T, Ut, g, bv, x0, x, out);
}

// Round 4
// 179.354 us; speedup vs baseline: 1.6208x; 1.6208x over previous
//
#include <hip/hip_runtime.h>
#include <math.h>

// Problem: B=16384, D=512, R=64, E=8.
// out = x0 * (sum_e g_e * (x @ V[e]^T C[e] U[e]^T)) + g@b + x*sum(g)
// Folded: VC[d, e*R+s] = sum_r V[e,r,d] C[e,r,s]  ->  xvc = x @ VC   (GEMM1)
//         t = g-scaled xvc (expert = col/64)      ->  gproj = t @ Ustack (GEMM2)
// R4: barrier-free K-loop. B-slab (64 cols x K=512 = 64 KB) staged to LDS ONCE;
//     A streamed global->VGPR fragments (16B/lane aligned). No __syncthreads in
//     the K-loop; no register-staged tiles (R3's spill disaster: VGPR_Count=40,
//     237 MB scratch writes). grid (128m, 8n): id%8 -> all n-blocks of an
//     m-slab + gemm1-writer/gemm2-reader of T share an XCD.

typedef __bf16 bf16_t;
typedef __attribute__((ext_vector_type(8))) __bf16 bf16x8;
typedef __attribute__((ext_vector_type(4))) __bf16 bf16x4;
typedef __attribute__((ext_vector_type(4))) float  floatx4;

// ---------------- K0: weight prep ------------------------------------------
__global__ __launch_bounds__(256) void prep_kernel(
    const float* __restrict__ U, const float* __restrict__ V, const float* __restrict__ C,
    bf16_t* __restrict__ VCc, bf16_t* __restrict__ Ut) {
  int tid = blockIdx.x * 256 + threadIdx.x;
  if (tid < 512 * 512) {
    int n = tid >> 9, d = tid & 511;
    int e = n >> 6, s = n & 63;
    const float* Vp = V + (size_t)e * 64 * 512 + d;   // V[e,r,d], stride 512 over r
    const float* Cp = C + (size_t)e * 64 * 64 + s;    // C[e,r,s], stride 64 over r
    float acc = 0.f;
#pragma unroll 8
    for (int r = 0; r < 64; ++r) acc += Vp[(size_t)r * 512] * Cp[r * 64];
    VCc[tid] = (bf16_t)acc;
  } else {
    int i2 = tid - 512 * 512;
    int d = i2 >> 9, n = i2 & 511;
    int e = n >> 6, s = n & 63;
    Ut[i2] = (bf16_t)U[((size_t)e * 512 + d) * 64 + s];
  }
}

// ---------------- K1: x -> bf16 cast + gate softmax (one wave per row) -----
__global__ __launch_bounds__(256) void gate_kernel(
    const float* __restrict__ x, const float* __restrict__ Wg, const float* __restrict__ bg,
    bf16_t* __restrict__ xbf, float* __restrict__ g) {
  int wave = threadIdx.x >> 6, lane = threadIdx.x & 63;
  int row = blockIdx.x * 4 + wave;
  const float4* xr = (const float4*)(x + (size_t)row * 512);
  float4 v0 = xr[lane];
  float4 v1 = xr[lane + 64];
  bf16x4* xb = (bf16x4*)(xbf + (size_t)row * 512);
  bf16x4 b0, b1;
  b0.x = (bf16_t)v0.x; b0.y = (bf16_t)v0.y; b0.z = (bf16_t)v0.z; b0.w = (bf16_t)v0.w;
  b1.x = (bf16_t)v1.x; b1.y = (bf16_t)v1.y; b1.z = (bf16_t)v1.z; b1.w = (bf16_t)v1.w;
  xb[lane] = b0;
  xb[lane + 64] = b1;
  float acc[8];
#pragma unroll
  for (int e = 0; e < 8; ++e) {
    const float4* wp = (const float4*)(Wg + (size_t)e * 512);
    float4 w0 = wp[lane], w1 = wp[lane + 64];
    acc[e] = v0.x * w0.x + v0.y * w0.y + v0.z * w0.z + v0.w * w0.w +
             v1.x * w1.x + v1.y * w1.y + v1.z * w1.z + v1.w * w1.w;
  }
#pragma unroll
  for (int e = 0; e < 8; ++e) {
#pragma unroll
    for (int off = 32; off > 0; off >>= 1) acc[e] += __shfl_xor(acc[e], off, 64);
  }
  float z[8], mx = -1e30f;
#pragma unroll
  for (int e = 0; e < 8; ++e) { z[e] = acc[e] + bg[e]; mx = fmaxf(mx, z[e]); }
  float s = 0.f;
#pragma unroll
  for (int e = 0; e < 8; ++e) { z[e] = __expf(z[e] - mx); s += z[e]; }
  float inv = 1.f / s;
  if (lane == 0) {
#pragma unroll
    for (int e = 0; e < 8; ++e) g[(size_t)row * 8 + e] = z[e] * inv;
  }
}

// ---------------- streaming GEMM core --------------------------------------
// A [M][512] bf16 row-major; Bt [N][512] bf16 (col n's K contiguous).
// Block tile 128m x 64n, 4 waves, wave = 32 rows (2 m-frags) x 64 cols (4 n-frags).
// LDS: B-slab 64x1024B, chunk c of col n stored at slot c^(n&7) -> frag reads 2-way (free).
// Staging: each wave writes one full col per i-step -> conflict-free.
__device__ __forceinline__ void gemm_stream(
    const bf16_t* __restrict__ A, const bf16_t* __restrict__ Bt,
    char* ldsB, int m0, int n0, int t, floatx4 acc[2][4]) {
  {
    const float4* src = (const float4*)(Bt + (size_t)n0 * 512);
#pragma unroll
    for (int i = 0; i < 16; ++i) {
      int G = i * 256 + t;
      int n = G >> 6, c = G & 63;
      *(float4*)(ldsB + n * 1024 + ((c ^ (n & 7)) << 4)) = src[G];
    }
  }
  __syncthreads();  // the only barrier before the epilogue
  const int lane = t & 63, wave = t >> 6;
  const int lhi = lane >> 4, llo = lane & 15;
  const char* pA0 = (const char*)A + (size_t)(m0 + wave * 32 + llo) * 1024 + lhi * 16;
  const char* pA1 = pA0 + 16 * 1024;
  const char* pB = ldsB + llo * 1024;
  const int bsw = (llo & 7) << 4;
#pragma unroll 4
  for (int ks = 0; ks < 16; ++ks) {
    bf16x8 a0 = *(const bf16x8*)(pA0 + ks * 64);
    bf16x8 a1 = *(const bf16x8*)(pA1 + ks * 64);
    bf16x8 bf[4];
#pragma unroll
    for (int nf = 0; nf < 4; ++nf)
      bf[nf] = *(const bf16x8*)(pB + nf * 16 * 1024 + ((((ks * 4 + lhi) << 4) ^ bsw)));
#pragma unroll
    for (int nf = 0; nf < 4; ++nf) {
      acc[0][nf] = __builtin_amdgcn_mfma_f32_16x16x32_bf16(a0, bf[nf], acc[0][nf], 0, 0, 0);
      acc[1][nf] = __builtin_amdgcn_mfma_f32_16x16x32_bf16(a1, bf[nf], acc[1][nf], 0, 0, 0);
    }
  }
}

// ---------------- K2: GEMM1 + gate-scale epilogue -> T (bf16) --------------
__global__ __launch_bounds__(256, 2) void gemm1_kernel(
    const bf16_t* __restrict__ xbf, const bf16_t* __restrict__ VCc,
    const float* __restrict__ g, bf16_t* __restrict__ T) {
  __shared__ char lds[65536];
  const int t = threadIdx.x;
  const int m0 = blockIdx.x * 128, n0 = blockIdx.y * 64;
  floatx4 acc[2][4];
#pragma unroll
  for (int i = 0; i < 2; ++i)
#pragma unroll
    for (int j = 0; j < 4; ++j) acc[i][j] = (floatx4){0.f, 0.f, 0.f, 0.f};
  gemm_stream(xbf, VCc, lds, m0, n0, t, acc);
  __syncthreads();  // K-loop LDS reads done; reuse lds for gate column
  float* gcol = (float*)lds;
  if (t < 128) gcol[t] = g[(size_t)(m0 + t) * 8 + (n0 >> 6)];
  __syncthreads();
  const int lane = t & 63, wave = t >> 6;
  const int lhi = lane >> 4, llo = lane & 15;
#pragma unroll
  for (int mf = 0; mf < 2; ++mf) {
#pragma unroll
    for (int r = 0; r < 4; ++r) {
      int rml = wave * 32 + mf * 16 + lhi * 4 + r;  // C/D: col=lane&15, row=quad*4+reg
      float gv = gcol[rml];
      size_t mrow = (size_t)(m0 + rml) * 512;
#pragma unroll
      for (int nf = 0; nf < 4; ++nf)
        T[mrow + n0 + nf * 16 + llo] = (bf16_t)(acc[mf][nf][r] * gv);
    }
  }
}

// ---------------- K3: GEMM2 + final epilogue -> out (f32) ------------------
__global__ __launch_bounds__(256, 2) void gemm2_kernel(
    const bf16_t* __restrict__ T, const bf16_t* __restrict__ Ut,
    const float* __restrict__ g, const float* __restrict__ bvec,
    const float* __restrict__ x0, const float* __restrict__ x,
    float* __restrict__ out) {
  __shared__ char lds[65536];
  const int t = threadIdx.x;
  const int m0 = blockIdx.x * 128, n0 = blockIdx.y * 64;
  floatx4 acc[2][4];
#pragma unroll
  for (int i = 0; i < 2; ++i)
#pragma unroll
    for (int j = 0; j < 4; ++j) acc[i][j] = (floatx4){0.f, 0.f, 0.f, 0.f};
  gemm_stream(T, Ut, lds, m0, n0, t, acc);
  __syncthreads();  // reuse lds: g-slab [128][8] (4KB) + b-slab [8][64] (2KB)
  float* ldsG = (float*)lds;
  float* ldsBv = (float*)(lds + 4096);
  ((float4*)ldsG)[t] = ((const float4*)(g + (size_t)m0 * 8))[t];
  if (t < 128)
    ((float4*)ldsBv)[t] = ((const float4*)bvec)[(t >> 4) * 128 + (n0 >> 2) + (t & 15)];
  __syncthreads();
  const int lane = t & 63, wave = t >> 6;
  const int lhi = lane >> 4, llo = lane & 15;
  float bb[4][8];
#pragma unroll
  for (int nf = 0; nf < 4; ++nf) {
    int nl = nf * 16 + llo;
#pragma unroll
    for (int e = 0; e < 8; ++e) bb[nf][e] = ldsBv[e * 64 + nl];
  }
#pragma unroll
  for (int mf = 0; mf < 2; ++mf) {
#pragma unroll
    for (int r = 0; r < 4; ++r) {
      int rml = wave * 32 + mf * 16 + lhi * 4 + r;
      float4 ga = ((const float4*)ldsG)[rml * 2];
      float4 gb2 = ((const float4*)ldsG)[rml * 2 + 1];
      float g8[8] = {ga.x, ga.y, ga.z, ga.w, gb2.x, gb2.y, gb2.z, gb2.w};
      float gsum = g8[0] + g8[1] + g8[2] + g8[3] + g8[4] + g8[5] + g8[6] + g8[7];
      size_t mrow = (size_t)(m0 + rml) * 512;
#pragma unroll
      for (int nf = 0; nf < 4; ++nf) {
        int n = n0 + nf * 16 + llo;
        float bias = 0.f;
#pragma unroll
        for (int e = 0; e < 8; ++e) bias += g8[e] * bb[nf][e];
        size_t idx = mrow + n;
        out[idx] = x0[idx] * acc[mf][nf][r] + bias + x[idx] * gsum;
      }
    }
  }
}

// ---------------- launch ----------------------------------------------------
extern "C" void kernel_launch(void* const* d_in, const int* in_sizes, int n_in,
                              void* d_out, int out_size, void* d_ws, size_t ws_size,
                              hipStream_t stream) {
  const float* x0 = (const float*)d_in[0];
  const float* x  = (const float*)d_in[1];
  const float* U  = (const float*)d_in[2];
  const float* V  = (const float*)d_in[3];
  const float* C  = (const float*)d_in[4];
  const float* bv = (const float*)d_in[5];
  const float* Wg = (const float*)d_in[6];
  const float* bg = (const float*)d_in[7];
  float* out = (float*)d_out;

  char* ws = (char*)d_ws;
  bf16_t* xbf = (bf16_t*)(ws);                               // 16,777,216 B
  bf16_t* T   = (bf16_t*)(ws + 16777216);                    // 16,777,216 B
  bf16_t* VCc = (bf16_t*)(ws + 33554432);                    //    524,288 B
  bf16_t* Ut  = (bf16_t*)(ws + 34078720);                    //    524,288 B
  float*  g   = (float*)(ws + 34603008);                     //    524,288 B

  prep_kernel<<<2048, 256, 0, stream>>>(U, V, C, VCc, Ut);
  gate_kernel<<<4096, 256, 0, stream>>>(x, Wg, bg, xbf, g);
  gemm1_kernel<<<dim3(128, 8), 256, 0, stream>>>(xbf, VCc, g, T);
  gemm2_kernel<<<dim3(128, 8), 256, 0, stream>>>(T, Ut, g, bv, x0, x, out);
}